// Round 8
// baseline (365.528 us; speedup 1.0000x reference)
//
#include <hip/hip_runtime.h>
#include <math.h>

// ---- problem constants ----
constexpr int kH    = 1024;
constexpr int kZ    = 1024;
constexpr int kA    = 4;
constexpr int kF    = 30;
constexpr int kDIN  = 2048;
constexpr int kDH   = 512;
constexpr int kEIN  = 1118;
constexpr int kEH   = 512;
constexpr int kEOUT = 94;

constexpr int GRU_NB  = 64;   // GRU blocks
constexpr int EXP_PRT = 8;    // partial-sum splits per expert (256 K-rows each)

// workspace layout (floats). TAG region is 8-byte packed (tag<<32)|h_bits;
// tags 1..30 can never equal 0xAAAAAAAA poison -> NO memset needed anywhere.
constexpr size_t HACC_OFF = 0;                                          // kF*2*8*kDH
constexpr size_t EHA_OFF  = HACC_OFF + (size_t)kF * 2 * EXP_PRT * kDH;  // 8*kEH
constexpr size_t TAG_OFF  = EHA_OFF + (size_t)8 * kEH;                  // kF*kH ull (16B-aligned)

typedef unsigned uint4e __attribute__((ext_vector_type(4)));

__device__ __forceinline__ float sigmoidf_(float x) { return 1.0f / (1.0f + __expf(-x)); }

__device__ __forceinline__ float wave_reduce(float v) {
#pragma unroll
  for (int off = 32; off > 0; off >>= 1) v += __shfl_down(v, off, 64);
  return v;
}

__device__ __forceinline__ void tag_st(unsigned long long* p, unsigned long long v) {
  __hip_atomic_store(p, v, __ATOMIC_RELAXED, __HIP_MEMORY_SCOPE_AGENT);
}

// one 16B agent-coherent load = TWO tagged entries per transaction
// (halves poll traffic vs two 8B atomic loads; each 8B half self-validates)
__device__ __forceinline__ uint4e poll16(const uint4e* p) {
  uint4e v;
  asm volatile("global_load_dwordx4 %0, %1, off sc1\n\ts_waitcnt vmcnt(0)"
               : "=v"(v) : "v"(p) : "memory");
  return v;
}

// ---------------- GRU: 64 blocks; 1 sync/step; weight loads hidden under poll ----------------
__global__ __launch_bounds__(512, 2) void gru64(const float* __restrict__ Whh,
                                                const float* __restrict__ bhh,
                                                const float* __restrict__ Wih,
                                                const float* __restrict__ bih,
                                                const float* __restrict__ a_t,
                                                const float* __restrict__ b_t,
                                                unsigned long long* __restrict__ tagbuf,
                                                const int* __restrict__ fptr) {
  const int bid  = blockIdx.x;
  const int tid  = threadIdx.x;
  const int wave = tid >> 6;
  const int lane = tid & 63;
  const int f    = *fptr;

  const int jb = bid * 16;
  const int j0 = jb + 2 * wave;   // ADJACENT rows per wave -> 16B tagged bundles
  const int j1 = j0 + 1;

  __shared__ float gis[kF][16][3];
  __shared__ __align__(16) float hsd[2][kH];   // double buffer: 1 syncthreads/step

  // gi[t][w][g] for this block's 16 rows (off critical path)
  for (int idx = tid; idx < kF * 16 * 3; idx += 512) {
    int t = idx / 48;
    int rem = idx - t * 48;
    int w = rem / 3, g = rem - w * 3;
    int r = jb + w + g * kH;
    float acc = bih[r];
    const float* wih = Wih + (size_t)r * kA;
    const float* at  = a_t + (size_t)t * kA;
#pragma unroll
    for (int k = 0; k < kA; k++) acc += wih[k] * at[k];
    gis[t][w][g] = acc;
  }
  __syncthreads();

  const float4* W4 = (const float4*)Whh;
  const float b0r = bhh[j0], b0z = bhh[j0 + kH], b0n = bhh[j0 + 2 * kH];
  const float b1r = bhh[j1], b1z = bhh[j1 + kH], b1n = bhh[j1 + 2 * kH];

  for (int t = 0; t < f; t++) {
    float* hsb = hsd[t & 1];

    // ---- issue this step's weight loads FIRST (no h dependency):
    // they complete under the poll wait, off the critical path.
    float4 wr0[4], wz0[4], wn0[4], wr1[4], wz1[4], wn1[4];
#pragma unroll
    for (int i = 0; i < 4; i++) {
      wr0[i] = W4[(size_t)j0 * 256 + i * 64 + lane];
      wz0[i] = W4[(size_t)(j0 + kH) * 256 + i * 64 + lane];
      wn0[i] = W4[(size_t)(j0 + 2 * kH) * 256 + i * 64 + lane];
      wr1[i] = W4[(size_t)j1 * 256 + i * 64 + lane];
      wz1[i] = W4[(size_t)(j1 + kH) * 256 + i * 64 + lane];
      wn1[i] = W4[(size_t)(j1 + 2 * kH) * 256 + i * 64 + lane];
    }

    // ---- acquire h_{t-1}: one dwordx4 poll per thread (2 tagged entries) ----
    if (t == 0) {
      hsb[tid]       = b_t[tid];
      hsb[tid + 512] = b_t[tid + 512];
    } else {
      const uint4e* tg = (const uint4e*)(tagbuf + (size_t)(t - 1) * kH);
      const unsigned want = (unsigned)t;  // step t-1 wrote tag t
      uint4e v = poll16(tg + tid);
      while (v.y != want || v.w != want) {
        __builtin_amdgcn_s_sleep(1);      // backoff: cut coherence-point pressure
        v = poll16(tg + tid);
      }
      hsb[2 * tid]     = __uint_as_float(v.x);
      hsb[2 * tid + 1] = __uint_as_float(v.z);
    }
    __syncthreads();

    // ---- compute this block's 16 rows ----
    const float4* hs4 = (const float4*)hsb;
    float a0r = 0.f, a0z = 0.f, a0n = 0.f, a1r = 0.f, a1z = 0.f, a1n = 0.f;
#pragma unroll
    for (int i = 0; i < 4; i++) {
      float4 h4 = hs4[i * 64 + lane];
      a0r += wr0[i].x * h4.x + wr0[i].y * h4.y + wr0[i].z * h4.z + wr0[i].w * h4.w;
      a0z += wz0[i].x * h4.x + wz0[i].y * h4.y + wz0[i].z * h4.z + wz0[i].w * h4.w;
      a0n += wn0[i].x * h4.x + wn0[i].y * h4.y + wn0[i].z * h4.z + wn0[i].w * h4.w;
      a1r += wr1[i].x * h4.x + wr1[i].y * h4.y + wr1[i].z * h4.z + wr1[i].w * h4.w;
      a1z += wz1[i].x * h4.x + wz1[i].y * h4.y + wz1[i].z * h4.z + wz1[i].w * h4.w;
      a1n += wn1[i].x * h4.x + wn1[i].y * h4.y + wn1[i].z * h4.z + wn1[i].w * h4.w;
    }
    a0r = wave_reduce(a0r); a0z = wave_reduce(a0z); a0n = wave_reduce(a0n);
    a1r = wave_reduce(a1r); a1z = wave_reduce(a1z); a1n = wave_reduce(a1n);

    if (lane == 0) {
      float rg = sigmoidf_(gis[t][2 * wave][0] + a0r + b0r);
      float zg = sigmoidf_(gis[t][2 * wave][1] + a0z + b0z);
      float ng = tanhf(gis[t][2 * wave][2] + rg * (a0n + b0n));
      float h0 = (1.0f - zg) * ng + zg * hsb[j0];
      rg = sigmoidf_(gis[t][2 * wave + 1][0] + a1r + b1r);
      zg = sigmoidf_(gis[t][2 * wave + 1][1] + a1z + b1z);
      ng = tanhf(gis[t][2 * wave + 1][2] + rg * (a1n + b1n));
      float h1 = (1.0f - zg) * ng + zg * hsb[j1];

      const unsigned long long tg = (unsigned long long)(unsigned)(t + 1) << 32;
      tag_st(tagbuf + (size_t)t * kH + j0, tg | (unsigned long long)__float_as_uint(h0));
      tag_st(tagbuf + (size_t)t * kH + j1, tg | (unsigned long long)__float_as_uint(h1));
    }
    // NO trailing syncthreads: next step fills hsd[(t+1)&1]; a wave cannot reach
    // step t+2 (which reuses this buffer) without all waves passing step t+1's sync.
  }
}

// ---------------- experts (240 blocks) + eval (8 blocks): pure streaming ----------------
__global__ __launch_bounds__(512) void experts(const float* __restrict__ zpos,
                                               const float* __restrict__ zneg,
                                               const unsigned long long* __restrict__ tagbuf,
                                               const float* __restrict__ W1,
                                               const float* __restrict__ b_t,
                                               const float* __restrict__ ipo,
                                               const float* __restrict__ eW1,
                                               float* __restrict__ hacc,
                                               float* __restrict__ ehacc,
                                               const int* __restrict__ fptr) {
  const int bid = blockIdx.x;
  const int tid = threadIdx.x;
  const int f   = *fptr;

  if (bid < kF * EXP_PRT) {
    __shared__ float xs_p[256];
    __shared__ float xs_n[256];
    int e = bid >> 3, part = bid & 7;
    if (e >= f) return;

    if (part < 4) {
      // z-half rows [part*256, part*256+256)
      int r0 = part * 256;
      if (tid < 256) {
        xs_p[tid] = zpos[(size_t)e * kZ + r0 + tid];
        xs_n[tid] = zneg[(size_t)e * kZ + r0 + tid];
      }
      __syncthreads();
      float ap = 0.f, an = 0.f;
      const float* w = W1 + ((size_t)e * kDIN + r0) * kDH + tid;
#pragma unroll 8
      for (int r = 0; r < 256; r++) {
        float wv = w[(size_t)r * kDH];
        ap += xs_p[r] * wv;
        an += xs_n[r] * wv;
      }
      hacc[(((size_t)e * 2 + 0) * EXP_PRT + part) * kDH + tid] = ap;
      hacc[(((size_t)e * 2 + 1) * EXP_PRT + part) * kDH + tid] = an;
    } else {
      // agru-half rows: h values live in tagbuf low words (finalized pre-launch)
      int r0 = (part - 4) * 256;
      if (tid < 256)
        xs_p[tid] = __uint_as_float((unsigned)tagbuf[(size_t)e * kH + r0 + tid]);
      __syncthreads();
      float a = 0.f;
      const float* w = W1 + ((size_t)e * kDIN + kZ + r0) * kDH + tid;
#pragma unroll 8
      for (int r = 0; r < 256; r++) a += xs_p[r] * w[(size_t)r * kDH];
      hacc[(((size_t)e * 2 + 0) * EXP_PRT + part) * kDH + tid] = a;
      hacc[(((size_t)e * 2 + 1) * EXP_PRT + part) * kDH + tid] = a;
    }
  } else {
    // eval first layer, 8 partial blocks
    __shared__ float evs[140];
    int part = bid - kF * EXP_PRT;  // 0..7
    int r0 = part * 140;
    int nr = min(140, kEIN - r0);
    if (tid < nr) {
      int r = r0 + tid;
      evs[tid] = (r < kH) ? b_t[r] : ipo[r - kH];
    }
    __syncthreads();
    float acc = 0.f;
    const float* w = eW1 + (size_t)r0 * kEH + tid;
    for (int r = 0; r < nr; r++) acc += evs[r] * w[(size_t)r * kEH];
    ehacc[(size_t)part * kEH + tid] = acc;
  }
}

// ---------------- stage2: second layers -> 2f+94 outputs ----------------
__global__ __launch_bounds__(512) void stage2(const float* __restrict__ hacc,
                                              const float* __restrict__ ehacc,
                                              const float* __restrict__ b1,
                                              const float* __restrict__ W2,
                                              const float* __restrict__ b2,
                                              const float* __restrict__ eb1,
                                              const float* __restrict__ eW2,
                                              const float* __restrict__ eb2,
                                              float* __restrict__ out,
                                              const int* __restrict__ fptr) {
  int b = blockIdx.x;
  int tid = threadIdx.x;
  int f = *fptr;
  if (b < kF) {
    int i = b;
    if (i >= f) return;
    float sp = 0.f, sn = 0.f;
#pragma unroll
    for (int p = 0; p < EXP_PRT; p++) {
      sp += hacc[(((size_t)i * 2 + 0) * EXP_PRT + p) * kDH + tid];
      sn += hacc[(((size_t)i * 2 + 1) * EXP_PRT + p) * kDH + tid];
    }
    float bias = b1[(size_t)i * kDH + tid];
    float hp = fmaxf(sp + bias, 0.f);
    float hn = fmaxf(sn + bias, 0.f);
    float w = W2[(size_t)i * kDH + tid];
    float pp = wave_reduce(hp * w);
    float pn = wave_reduce(hn * w);
    __shared__ float redp[8];
    __shared__ float redn[8];
    int wave = tid >> 6, lane = tid & 63;
    if (lane == 0) { redp[wave] = pp; redn[wave] = pn; }
    __syncthreads();
    if (tid == 0) {
      float s0 = 0.f, s1 = 0.f;
#pragma unroll
      for (int k = 0; k < 8; k++) { s0 += redp[k]; s1 += redn[k]; }
      out[i] = s0 + b2[i];
      out[f + i] = s1 + b2[i];
    }
  } else {
    // eval second layer: reduce 8 partials cooperatively, then 94 outputs
    __shared__ float ehs[kEH];
    {
      float s = eb1[tid];
#pragma unroll
      for (int p = 0; p < 8; p++) s += ehacc[(size_t)p * kEH + tid];
      ehs[tid] = fmaxf(s, 0.f);
    }
    __syncthreads();
    if (tid < kEOUT) {
      float acc = eb2[tid];
      for (int h = 0; h < kEH; h++) acc += ehs[h] * eW2[(size_t)h * kEOUT + tid];
      out[2 * f + tid] = sigmoidf_(acc);
    }
  }
}

extern "C" void kernel_launch(void* const* d_in, const int* in_sizes, int n_in,
                              void* d_out, int out_size, void* d_ws, size_t ws_size,
                              hipStream_t stream) {
  const float* b_t  = (const float*)d_in[0];
  const float* a_t  = (const float*)d_in[1];
  const float* zpos = (const float*)d_in[2];
  const float* zneg = (const float*)d_in[3];
  const float* ipo  = (const float*)d_in[4];
  const float* gWih = (const float*)d_in[5];
  const float* gWhh = (const float*)d_in[6];
  const float* gbih = (const float*)d_in[7];
  const float* gbhh = (const float*)d_in[8];
  const float* mW1  = (const float*)d_in[9];
  const float* mb1  = (const float*)d_in[10];
  const float* mW2  = (const float*)d_in[11];
  const float* mb2  = (const float*)d_in[12];
  const float* eW1  = (const float*)d_in[13];
  const float* eb1  = (const float*)d_in[14];
  const float* eW2  = (const float*)d_in[15];
  const float* eb2  = (const float*)d_in[16];
  const int*   fptr = (const int*)d_in[17];

  float* ws     = (float*)d_ws;
  float* hacc   = ws + HACC_OFF;
  float* ehacc  = ws + EHA_OFF;
  unsigned long long* tagbuf = (unsigned long long*)(ws + TAG_OFF);
  float* out    = (float*)d_out;

  // 1) GRU: dwordx4 tagged polls + backoff, weight loads hidden under poll
  gru64<<<GRU_NB, 512, 0, stream>>>(gWhh, gbhh, gWih, gbih, a_t, b_t, tagbuf, fptr);

  // 2) expert + eval first layers: pure HBM streaming, no waits
  experts<<<kF * EXP_PRT + 8, 512, 0, stream>>>(zpos, zneg, tagbuf, mW1, b_t, ipo, eW1,
                                                hacc, ehacc, fptr);

  // 3) second layers -> outputs
  stage2<<<kF + 1, 512, 0, stream>>>(hacc, ehacc, mb1, mW2, mb2, eb1, eW2, eb2, out, fptr);
}

// Round 9
// 351.603 us; speedup vs baseline: 1.0396x; 1.0396x over previous
//
#include <hip/hip_runtime.h>
#include <math.h>

// ---- problem constants ----
constexpr int kH    = 1024;
constexpr int kZ    = 1024;
constexpr int kA    = 4;
constexpr int kF    = 30;
constexpr int kDIN  = 2048;
constexpr int kDH   = 512;
constexpr int kEIN  = 1118;
constexpr int kEH   = 512;
constexpr int kEOUT = 94;

constexpr int GRU_NB  = 64;   // GRU blocks
constexpr int EXP_PRT = 8;    // partial-sum splits per expert (256 K-rows each)

// workspace layout (floats). TAG region is 8-byte packed (tag<<32)|h_bits;
// tags 1..30 can never equal 0xAAAAAAAA poison -> NO memset needed anywhere.
constexpr size_t HACC_OFF = 0;                                          // kF*2*8*kDH
constexpr size_t EHA_OFF  = HACC_OFF + (size_t)kF * 2 * EXP_PRT * kDH;  // 8*kEH
constexpr size_t TAG_OFF  = EHA_OFF + (size_t)8 * kEH;                  // kF*kH ull (8B-aligned)

__device__ __forceinline__ float sigmoidf_(float x) { return 1.0f / (1.0f + __expf(-x)); }

__device__ __forceinline__ float wave_reduce(float v) {
#pragma unroll
  for (int off = 32; off > 0; off >>= 1) v += __shfl_down(v, off, 64);
  return v;
}

__device__ __forceinline__ unsigned long long tag_ld(const unsigned long long* p) {
  return __hip_atomic_load(p, __ATOMIC_RELAXED, __HIP_MEMORY_SCOPE_AGENT);
}

// THE round-9 variable: publish via fire-and-forget atomic exchange (RMW).
// RMWs execute AT the coherence point -> no L2-writeback visibility lag.
// (r5-r8 constancy at ~3.6-4 us/step across wildly different protocols points
//  at plain sc1 stores lingering dirty in the producer XCD's L2.)
__device__ __forceinline__ void tag_pub(unsigned long long* p, unsigned long long v) {
  (void)__hip_atomic_exchange(p, v, __ATOMIC_RELAXED, __HIP_MEMORY_SCOPE_AGENT);
}

// ---------------- GRU: 64 blocks; r6 structure + RMW publish ----------------
__global__ __launch_bounds__(512) void gru64(const float* __restrict__ Whh,
                                             const float* __restrict__ bhh,
                                             const float* __restrict__ Wih,
                                             const float* __restrict__ bih,
                                             const float* __restrict__ a_t,
                                             const float* __restrict__ b_t,
                                             unsigned long long* __restrict__ tagbuf,
                                             const int* __restrict__ fptr) {
  const int bid  = blockIdx.x;
  const int tid  = threadIdx.x;
  const int wave = tid >> 6;
  const int lane = tid & 63;
  const int f    = *fptr;

  const int jb = bid * 16;
  const int j0 = jb + wave;       // rows j0 and j1 = j0+8
  const int j1 = jb + wave + 8;

  __shared__ float gis[kF][16][3];
  __shared__ __align__(16) float hs[kH];

  const float4* W4 = (const float4*)Whh;
  float4 wr0[4], wz0[4], wn0[4], wr1[4], wz1[4], wn1[4];
#pragma unroll
  for (int i = 0; i < 4; i++) {
    wr0[i] = W4[(size_t)j0 * 256 + i * 64 + lane];
    wz0[i] = W4[(size_t)(j0 + kH) * 256 + i * 64 + lane];
    wn0[i] = W4[(size_t)(j0 + 2 * kH) * 256 + i * 64 + lane];
    wr1[i] = W4[(size_t)j1 * 256 + i * 64 + lane];
    wz1[i] = W4[(size_t)(j1 + kH) * 256 + i * 64 + lane];
    wn1[i] = W4[(size_t)(j1 + 2 * kH) * 256 + i * 64 + lane];
  }
  const float b0r = bhh[j0], b0z = bhh[j0 + kH], b0n = bhh[j0 + 2 * kH];
  const float b1r = bhh[j1], b1z = bhh[j1 + kH], b1n = bhh[j1 + 2 * kH];

  // gi[t][w][g] for this block's 16 rows (off critical path)
  for (int idx = tid; idx < kF * 16 * 3; idx += 512) {
    int t = idx / 48;
    int rem = idx - t * 48;
    int w = rem / 3, g = rem - w * 3;
    int r = jb + w + g * kH;
    float acc = bih[r];
    const float* wih = Wih + (size_t)r * kA;
    const float* at  = a_t + (size_t)t * kA;
#pragma unroll
    for (int k = 0; k < kA; k++) acc += wih[k] * at[k];
    gis[t][w][g] = acc;
  }
  __syncthreads();

  const float4* hs4 = (const float4*)hs;
  for (int t = 0; t < f; t++) {
    // ---- acquire h_{t-1}: poll the self-validating tagged data ----
    if (t == 0) {
      hs[tid]       = b_t[tid];
      hs[tid + 512] = b_t[tid + 512];
    } else {
      const unsigned long long* tg = tagbuf + (size_t)(t - 1) * kH;
      const unsigned want = (unsigned)t;  // step t-1 wrote tag t
      unsigned long long v0 = tag_ld(tg + tid);
      unsigned long long v1 = tag_ld(tg + tid + 512);
      while ((unsigned)(v0 >> 32) != want) v0 = tag_ld(tg + tid);
      while ((unsigned)(v1 >> 32) != want) v1 = tag_ld(tg + tid + 512);
      hs[tid]       = __uint_as_float((unsigned)v0);
      hs[tid + 512] = __uint_as_float((unsigned)v1);
    }
    __syncthreads();

    // ---- compute this block's 16 rows ----
    float a0r = 0.f, a0z = 0.f, a0n = 0.f, a1r = 0.f, a1z = 0.f, a1n = 0.f;
#pragma unroll
    for (int i = 0; i < 4; i++) {
      float4 h4 = hs4[i * 64 + lane];
      a0r += wr0[i].x * h4.x + wr0[i].y * h4.y + wr0[i].z * h4.z + wr0[i].w * h4.w;
      a0z += wz0[i].x * h4.x + wz0[i].y * h4.y + wz0[i].z * h4.z + wz0[i].w * h4.w;
      a0n += wn0[i].x * h4.x + wn0[i].y * h4.y + wn0[i].z * h4.z + wn0[i].w * h4.w;
      a1r += wr1[i].x * h4.x + wr1[i].y * h4.y + wr1[i].z * h4.z + wr1[i].w * h4.w;
      a1z += wz1[i].x * h4.x + wz1[i].y * h4.y + wz1[i].z * h4.z + wz1[i].w * h4.w;
      a1n += wn1[i].x * h4.x + wn1[i].y * h4.y + wn1[i].z * h4.z + wn1[i].w * h4.w;
    }
    a0r = wave_reduce(a0r); a0z = wave_reduce(a0z); a0n = wave_reduce(a0n);
    a1r = wave_reduce(a1r); a1z = wave_reduce(a1z); a1n = wave_reduce(a1n);

    if (lane == 0) {
      float rg = sigmoidf_(gis[t][wave][0] + a0r + b0r);
      float zg = sigmoidf_(gis[t][wave][1] + a0z + b0z);
      float ng = tanhf(gis[t][wave][2] + rg * (a0n + b0n));
      float h0 = (1.0f - zg) * ng + zg * hs[j0];
      rg = sigmoidf_(gis[t][wave + 8][0] + a1r + b1r);
      zg = sigmoidf_(gis[t][wave + 8][1] + a1z + b1z);
      ng = tanhf(gis[t][wave + 8][2] + rg * (a1n + b1n));
      float h1 = (1.0f - zg) * ng + zg * hs[j1];

      const unsigned long long tg = (unsigned long long)(unsigned)(t + 1) << 32;
      tag_pub(tagbuf + (size_t)t * kH + j0, tg | (unsigned long long)__float_as_uint(h0));
      tag_pub(tagbuf + (size_t)t * kH + j1, tg | (unsigned long long)__float_as_uint(h1));
    }
    __syncthreads();  // all waves done reading hs before next-step refill
  }
}

// ---------------- experts (240 blocks) + eval (8 blocks): pure streaming ----------------
__global__ __launch_bounds__(512) void experts(const float* __restrict__ zpos,
                                               const float* __restrict__ zneg,
                                               const unsigned long long* __restrict__ tagbuf,
                                               const float* __restrict__ W1,
                                               const float* __restrict__ b_t,
                                               const float* __restrict__ ipo,
                                               const float* __restrict__ eW1,
                                               float* __restrict__ hacc,
                                               float* __restrict__ ehacc,
                                               const int* __restrict__ fptr) {
  const int bid = blockIdx.x;
  const int tid = threadIdx.x;
  const int f   = *fptr;

  if (bid < kF * EXP_PRT) {
    __shared__ float xs_p[256];
    __shared__ float xs_n[256];
    int e = bid >> 3, part = bid & 7;
    if (e >= f) return;

    if (part < 4) {
      // z-half rows [part*256, part*256+256)
      int r0 = part * 256;
      if (tid < 256) {
        xs_p[tid] = zpos[(size_t)e * kZ + r0 + tid];
        xs_n[tid] = zneg[(size_t)e * kZ + r0 + tid];
      }
      __syncthreads();
      float ap = 0.f, an = 0.f;
      const float* w = W1 + ((size_t)e * kDIN + r0) * kDH + tid;
#pragma unroll 8
      for (int r = 0; r < 256; r++) {
        float wv = w[(size_t)r * kDH];
        ap += xs_p[r] * wv;
        an += xs_n[r] * wv;
      }
      hacc[(((size_t)e * 2 + 0) * EXP_PRT + part) * kDH + tid] = ap;
      hacc[(((size_t)e * 2 + 1) * EXP_PRT + part) * kDH + tid] = an;
    } else {
      // agru-half rows: h values live in tagbuf low words (finalized pre-launch)
      int r0 = (part - 4) * 256;
      if (tid < 256)
        xs_p[tid] = __uint_as_float((unsigned)tagbuf[(size_t)e * kH + r0 + tid]);
      __syncthreads();
      float a = 0.f;
      const float* w = W1 + ((size_t)e * kDIN + kZ + r0) * kDH + tid;
#pragma unroll 8
      for (int r = 0; r < 256; r++) a += xs_p[r] * w[(size_t)r * kDH];
      hacc[(((size_t)e * 2 + 0) * EXP_PRT + part) * kDH + tid] = a;
      hacc[(((size_t)e * 2 + 1) * EXP_PRT + part) * kDH + tid] = a;
    }
  } else {
    // eval first layer, 8 partial blocks
    __shared__ float evs[140];
    int part = bid - kF * EXP_PRT;  // 0..7
    int r0 = part * 140;
    int nr = min(140, kEIN - r0);
    if (tid < nr) {
      int r = r0 + tid;
      evs[tid] = (r < kH) ? b_t[r] : ipo[r - kH];
    }
    __syncthreads();
    float acc = 0.f;
    const float* w = eW1 + (size_t)r0 * kEH + tid;
    for (int r = 0; r < nr; r++) acc += evs[r] * w[(size_t)r * kEH];
    ehacc[(size_t)part * kEH + tid] = acc;
  }
}

// ---------------- stage2: second layers -> 2f+94 outputs ----------------
__global__ __launch_bounds__(512) void stage2(const float* __restrict__ hacc,
                                              const float* __restrict__ ehacc,
                                              const float* __restrict__ b1,
                                              const float* __restrict__ W2,
                                              const float* __restrict__ b2,
                                              const float* __restrict__ eb1,
                                              const float* __restrict__ eW2,
                                              const float* __restrict__ eb2,
                                              float* __restrict__ out,
                                              const int* __restrict__ fptr) {
  int b = blockIdx.x;
  int tid = threadIdx.x;
  int f = *fptr;
  if (b < kF) {
    int i = b;
    if (i >= f) return;
    float sp = 0.f, sn = 0.f;
#pragma unroll
    for (int p = 0; p < EXP_PRT; p++) {
      sp += hacc[(((size_t)i * 2 + 0) * EXP_PRT + p) * kDH + tid];
      sn += hacc[(((size_t)i * 2 + 1) * EXP_PRT + p) * kDH + tid];
    }
    float bias = b1[(size_t)i * kDH + tid];
    float hp = fmaxf(sp + bias, 0.f);
    float hn = fmaxf(sn + bias, 0.f);
    float w = W2[(size_t)i * kDH + tid];
    float pp = wave_reduce(hp * w);
    float pn = wave_reduce(hn * w);
    __shared__ float redp[8];
    __shared__ float redn[8];
    int wave = tid >> 6, lane = tid & 63;
    if (lane == 0) { redp[wave] = pp; redn[wave] = pn; }
    __syncthreads();
    if (tid == 0) {
      float s0 = 0.f, s1 = 0.f;
#pragma unroll
      for (int k = 0; k < 8; k++) { s0 += redp[k]; s1 += redn[k]; }
      out[i] = s0 + b2[i];
      out[f + i] = s1 + b2[i];
    }
  } else {
    // eval second layer: reduce 8 partials cooperatively, then 94 outputs
    __shared__ float ehs[kEH];
    {
      float s = eb1[tid];
#pragma unroll
      for (int p = 0; p < 8; p++) s += ehacc[(size_t)p * kEH + tid];
      ehs[tid] = fmaxf(s, 0.f);
    }
    __syncthreads();
    if (tid < kEOUT) {
      float acc = eb2[tid];
      for (int h = 0; h < kEH; h++) acc += ehs[h] * eW2[(size_t)h * kEOUT + tid];
      out[2 * f + tid] = sigmoidf_(acc);
    }
  }
}

extern "C" void kernel_launch(void* const* d_in, const int* in_sizes, int n_in,
                              void* d_out, int out_size, void* d_ws, size_t ws_size,
                              hipStream_t stream) {
  const float* b_t  = (const float*)d_in[0];
  const float* a_t  = (const float*)d_in[1];
  const float* zpos = (const float*)d_in[2];
  const float* zneg = (const float*)d_in[3];
  const float* ipo  = (const float*)d_in[4];
  const float* gWih = (const float*)d_in[5];
  const float* gWhh = (const float*)d_in[6];
  const float* gbih = (const float*)d_in[7];
  const float* gbhh = (const float*)d_in[8];
  const float* mW1  = (const float*)d_in[9];
  const float* mb1  = (const float*)d_in[10];
  const float* mW2  = (const float*)d_in[11];
  const float* mb2  = (const float*)d_in[12];
  const float* eW1  = (const float*)d_in[13];
  const float* eb1  = (const float*)d_in[14];
  const float* eW2  = (const float*)d_in[15];
  const float* eb2  = (const float*)d_in[16];
  const int*   fptr = (const int*)d_in[17];

  float* ws     = (float*)d_ws;
  float* hacc   = ws + HACC_OFF;
  float* ehacc  = ws + EHA_OFF;
  unsigned long long* tagbuf = (unsigned long long*)(ws + TAG_OFF);
  float* out    = (float*)d_out;

  // 1) GRU: r6 structure, publish via coherence-point RMW (atomicExch)
  gru64<<<GRU_NB, 512, 0, stream>>>(gWhh, gbhh, gWih, gbih, a_t, b_t, tagbuf, fptr);

  // 2) expert + eval first layers: pure HBM streaming, no waits
  experts<<<kF * EXP_PRT + 8, 512, 0, stream>>>(zpos, zneg, tagbuf, mW1, b_t, ipo, eW1,
                                                hacc, ehacc, fptr);

  // 3) second layers -> outputs
  stage2<<<kF + 1, 512, 0, stream>>>(hacc, ehacc, mb1, mW2, mb2, eb1, eW2, eb2, out, fptr);
}

// Round 11
// 342.725 us; speedup vs baseline: 1.0665x; 1.0259x over previous
//
#include <hip/hip_runtime.h>
#include <math.h>

// ---- problem constants ----
constexpr int kH    = 1024;
constexpr int kZ    = 1024;
constexpr int kA    = 4;
constexpr int kF    = 30;
constexpr int kDIN  = 2048;
constexpr int kDH   = 512;
constexpr int kEIN  = 1118;
constexpr int kEH   = 512;
constexpr int kEOUT = 94;

constexpr int GRU_NB = 128;  // GRU blocks (1/CU, all co-resident on 256 CUs)
constexpr int RPB    = 8;    // hidden rows per block (1 per wave)
constexpr int EXP_PRT = 8;   // partial-sum splits per expert

// workspace layout (floats). TAG region is 8-byte packed (tag<<32)|h_bits;
// tags 1..30 can never equal 0xAAAAAAAA poison -> NO memset needed anywhere.
constexpr size_t HACC_OFF = 0;                                          // kF*2*8*kDH
constexpr size_t EHA_OFF  = HACC_OFF + (size_t)kF * 2 * EXP_PRT * kDH;  // 8*kEH
constexpr size_t TAG_OFF  = EHA_OFF + (size_t)8 * kEH;                  // kF*kH ull (8B-aligned)

__device__ __forceinline__ float sigmoidf_(float x) { return 1.0f / (1.0f + __expf(-x)); }

__device__ __forceinline__ float wave_reduce(float v) {
#pragma unroll
  for (int off = 32; off > 0; off >>= 1) v += __shfl_down(v, off, 64);
  return v;
}

__device__ __forceinline__ unsigned long long tag_ld(const unsigned long long* p) {
  return __hip_atomic_load(p, __ATOMIC_RELAXED, __HIP_MEMORY_SCOPE_AGENT);
}
__device__ __forceinline__ void tag_st(unsigned long long* p, unsigned long long v) {
  __hip_atomic_store(p, v, __ATOMIC_RELAXED, __HIP_MEMORY_SCOPE_AGENT);
}

// ---------------- GRU: 128 blocks; Whh rows LDS-resident (the r5-r9 constant
// ~3.6us/step decomposes as ~1.5us L2 weight re-stream + ~2us sync; this kills
// the first term deterministically -- VGPR residency proved uncontrollable) ----
__global__ __launch_bounds__(512) void gru128(const float* __restrict__ Whh,
                                              const float* __restrict__ bhh,
                                              const float* __restrict__ Wih,
                                              const float* __restrict__ bih,
                                              const float* __restrict__ a_t,
                                              const float* __restrict__ b_t,
                                              unsigned long long* __restrict__ tagbuf,
                                              const int* __restrict__ fptr) {
  const int bid  = blockIdx.x;
  const int tid  = threadIdx.x;
  const int wave = tid >> 6;
  const int lane = tid & 63;
  const int f    = *fptr;

  const int jb = bid * RPB;
  const int j  = jb + wave;  // this wave's hidden row

  __shared__ float4 wlds[RPB * 3 * 256];          // 96 KB: 8 rows x 3 gates x 1024 f32
  __shared__ float gis[kF][RPB][3];               // 2.9 KB
  __shared__ __align__(16) float hs[kH];          // 4 KB

  // ---- one-time: stage this block's Whh rows into LDS (coalesced float4) ----
  const float4* W4 = (const float4*)Whh;
  for (int idx = tid; idx < RPB * 3 * 256; idx += 512) {
    int r = idx / 768;
    int rem = idx - r * 768;
    int g = rem >> 8;
    int i = rem & 255;
    wlds[idx] = W4[(size_t)(jb + r + g * kH) * 256 + i];
  }

  // ---- one-time: gi[t][w][g] for this block's 8 rows ----
  for (int idx = tid; idx < kF * RPB * 3; idx += 512) {
    int t = idx / 24;
    int rem = idx - t * 24;
    int w = rem / 3, g = rem - w * 3;
    int r = jb + w + g * kH;
    float acc = bih[r];
    const float* wih = Wih + (size_t)r * kA;
    const float* at  = a_t + (size_t)t * kA;
#pragma unroll
    for (int k = 0; k < kA; k++) acc += wih[k] * at[k];
    gis[t][w][g] = acc;
  }
  __syncthreads();

  const float4* wr = wlds + (wave * 3 + 0) * 256;
  const float4* wz = wlds + (wave * 3 + 1) * 256;
  const float4* wn = wlds + (wave * 3 + 2) * 256;
  const float br = bhh[j], bz = bhh[j + kH], bn = bhh[j + 2 * kH];
  const float4* hs4 = (const float4*)hs;

  for (int t = 0; t < f; t++) {
    // ---- acquire h_{t-1}: poll the self-validating tagged data (r6 protocol) ----
    if (t == 0) {
      hs[tid]       = b_t[tid];
      hs[tid + 512] = b_t[tid + 512];
    } else {
      const unsigned long long* tg = tagbuf + (size_t)(t - 1) * kH;
      const unsigned want = (unsigned)t;  // step t-1 wrote tag t
      unsigned long long v0 = tag_ld(tg + tid);
      unsigned long long v1 = tag_ld(tg + tid + 512);
      while ((unsigned)(v0 >> 32) != want) v0 = tag_ld(tg + tid);
      while ((unsigned)(v1 >> 32) != want) v1 = tag_ld(tg + tid + 512);
      hs[tid]       = __uint_as_float((unsigned)v0);
      hs[tid + 512] = __uint_as_float((unsigned)v1);
    }
    __syncthreads();

    // ---- compute this wave's row: 3 dots of 1024, all operands in LDS ----
    float ar = 0.f, az = 0.f, an = 0.f;
#pragma unroll
    for (int i = 0; i < 4; i++) {
      float4 h4 = hs4[i * 64 + lane];
      float4 a = wr[i * 64 + lane];
      float4 b = wz[i * 64 + lane];
      float4 c = wn[i * 64 + lane];
      ar += a.x * h4.x + a.y * h4.y + a.z * h4.z + a.w * h4.w;
      az += b.x * h4.x + b.y * h4.y + b.z * h4.z + b.w * h4.w;
      an += c.x * h4.x + c.y * h4.y + c.z * h4.z + c.w * h4.w;
    }
    ar = wave_reduce(ar);
    az = wave_reduce(az);
    an = wave_reduce(an);

    if (lane == 0) {
      float rg = sigmoidf_(gis[t][wave][0] + ar + br);
      float zg = sigmoidf_(gis[t][wave][1] + az + bz);
      float ng = tanhf(gis[t][wave][2] + rg * (an + bn));
      float hn = (1.0f - zg) * ng + zg * hs[j];
      tag_st(tagbuf + (size_t)t * kH + j,
             ((unsigned long long)(unsigned)(t + 1) << 32) |
                 (unsigned long long)__float_as_uint(hn));
    }
    __syncthreads();  // all waves done reading hs before next-step refill
  }
}

// ---------------- experts (240 blocks) + eval (8 blocks): pure streaming ----------------
__global__ __launch_bounds__(512) void experts(const float* __restrict__ zpos,
                                               const float* __restrict__ zneg,
                                               const unsigned long long* __restrict__ tagbuf,
                                               const float* __restrict__ W1,
                                               const float* __restrict__ b_t,
                                               const float* __restrict__ ipo,
                                               const float* __restrict__ eW1,
                                               float* __restrict__ hacc,
                                               float* __restrict__ ehacc,
                                               const int* __restrict__ fptr) {
  const int bid = blockIdx.x;
  const int tid = threadIdx.x;
  const int f   = *fptr;

  if (bid < kF * EXP_PRT) {
    __shared__ float xs_p[256];
    __shared__ float xs_n[256];
    int e = bid >> 3, part = bid & 7;
    if (e >= f) return;

    if (part < 4) {
      // z-half rows [part*256, part*256+256)
      int r0 = part * 256;
      if (tid < 256) {
        xs_p[tid] = zpos[(size_t)e * kZ + r0 + tid];
        xs_n[tid] = zneg[(size_t)e * kZ + r0 + tid];
      }
      __syncthreads();
      float ap = 0.f, an = 0.f;
      const float* w = W1 + ((size_t)e * kDIN + r0) * kDH + tid;
#pragma unroll 8
      for (int r = 0; r < 256; r++) {
        float wv = w[(size_t)r * kDH];
        ap += xs_p[r] * wv;
        an += xs_n[r] * wv;
      }
      hacc[(((size_t)e * 2 + 0) * EXP_PRT + part) * kDH + tid] = ap;
      hacc[(((size_t)e * 2 + 1) * EXP_PRT + part) * kDH + tid] = an;
    } else {
      // agru-half rows: h values live in tagbuf low words (finalized pre-launch)
      int r0 = (part - 4) * 256;
      if (tid < 256)
        xs_p[tid] = __uint_as_float((unsigned)tagbuf[(size_t)e * kH + r0 + tid]);
      __syncthreads();
      float a = 0.f;
      const float* w = W1 + ((size_t)e * kDIN + kZ + r0) * kDH + tid;
#pragma unroll 8
      for (int r = 0; r < 256; r++) a += xs_p[r] * w[(size_t)r * kDH];
      hacc[(((size_t)e * 2 + 0) * EXP_PRT + part) * kDH + tid] = a;
      hacc[(((size_t)e * 2 + 1) * EXP_PRT + part) * kDH + tid] = a;
    }
  } else {
    // eval first layer, 8 partial blocks
    __shared__ float evs[140];
    int part = bid - kF * EXP_PRT;  // 0..7
    int r0 = part * 140;
    int nr = min(140, kEIN - r0);
    if (tid < nr) {
      int r = r0 + tid;
      evs[tid] = (r < kH) ? b_t[r] : ipo[r - kH];
    }
    __syncthreads();
    float acc = 0.f;
    const float* w = eW1 + (size_t)r0 * kEH + tid;
    for (int r = 0; r < nr; r++) acc += evs[r] * w[(size_t)r * kEH];
    ehacc[(size_t)part * kEH + tid] = acc;
  }
}

// ---------------- stage2: second layers -> 2f+94 outputs ----------------
__global__ __launch_bounds__(512) void stage2(const float* __restrict__ hacc,
                                              const float* __restrict__ ehacc,
                                              const float* __restrict__ b1,
                                              const float* __restrict__ W2,
                                              const float* __restrict__ b2,
                                              const float* __restrict__ eb1,
                                              const float* __restrict__ eW2,
                                              const float* __restrict__ eb2,
                                              float* __restrict__ out,
                                              const int* __restrict__ fptr) {
  int b = blockIdx.x;
  int tid = threadIdx.x;
  int f = *fptr;
  if (b < kF) {
    int i = b;
    if (i >= f) return;
    float sp = 0.f, sn = 0.f;
#pragma unroll
    for (int p = 0; p < EXP_PRT; p++) {
      sp += hacc[(((size_t)i * 2 + 0) * EXP_PRT + p) * kDH + tid];
      sn += hacc[(((size_t)i * 2 + 1) * EXP_PRT + p) * kDH + tid];
    }
    float bias = b1[(size_t)i * kDH + tid];
    float hp = fmaxf(sp + bias, 0.f);
    float hn = fmaxf(sn + bias, 0.f);
    float w = W2[(size_t)i * kDH + tid];
    float pp = wave_reduce(hp * w);
    float pn = wave_reduce(hn * w);
    __shared__ float redp[8];
    __shared__ float redn[8];
    int wave = tid >> 6, lane = tid & 63;
    if (lane == 0) { redp[wave] = pp; redn[wave] = pn; }
    __syncthreads();
    if (tid == 0) {
      float s0 = 0.f, s1 = 0.f;
#pragma unroll
      for (int k = 0; k < 8; k++) { s0 += redp[k]; s1 += redn[k]; }
      out[i] = s0 + b2[i];
      out[f + i] = s1 + b2[i];
    }
  } else {
    // eval second layer: reduce 8 partials cooperatively, then 94 outputs
    __shared__ float ehs[kEH];
    {
      float s = eb1[tid];
#pragma unroll
      for (int p = 0; p < 8; p++) s += ehacc[(size_t)p * kEH + tid];
      ehs[tid] = fmaxf(s, 0.f);
    }
    __syncthreads();
    if (tid < kEOUT) {
      float acc = eb2[tid];
      for (int h = 0; h < kEH; h++) acc += ehs[h] * eW2[(size_t)h * kEOUT + tid];
      out[2 * f + tid] = sigmoidf_(acc);
    }
  }
}

extern "C" void kernel_launch(void* const* d_in, const int* in_sizes, int n_in,
                              void* d_out, int out_size, void* d_ws, size_t ws_size,
                              hipStream_t stream) {
  const float* b_t  = (const float*)d_in[0];
  const float* a_t  = (const float*)d_in[1];
  const float* zpos = (const float*)d_in[2];
  const float* zneg = (const float*)d_in[3];
  const float* ipo  = (const float*)d_in[4];
  const float* gWih = (const float*)d_in[5];
  const float* gWhh = (const float*)d_in[6];
  const float* gbih = (const float*)d_in[7];
  const float* gbhh = (const float*)d_in[8];
  const float* mW1  = (const float*)d_in[9];
  const float* mb1  = (const float*)d_in[10];
  const float* mW2  = (const float*)d_in[11];
  const float* mb2  = (const float*)d_in[12];
  const float* eW1  = (const float*)d_in[13];
  const float* eb1  = (const float*)d_in[14];
  const float* eW2  = (const float*)d_in[15];
  const float* eb2  = (const float*)d_in[16];
  const int*   fptr = (const int*)d_in[17];

  float* ws     = (float*)d_ws;
  float* hacc   = ws + HACC_OFF;
  float* ehacc  = ws + EHA_OFF;
  unsigned long long* tagbuf = (unsigned long long*)(ws + TAG_OFF);
  float* out    = (float*)d_out;

  // 1) GRU: LDS-resident weights, r6 tagged-poll sync
  gru128<<<GRU_NB, 512, 0, stream>>>(gWhh, gbhh, gWih, gbih, a_t, b_t, tagbuf, fptr);

  // 2) expert + eval first layers: pure HBM streaming, no waits
  experts<<<kF * EXP_PRT + 8, 512, 0, stream>>>(zpos, zneg, tagbuf, mW1, b_t, ipo, eW1,
                                                hacc, ehacc, fptr);

  // 3) second layers -> outputs
  stage2<<<kF + 1, 512, 0, stream>>>(hacc, ehacc, mb1, mW2, mb2, eb1, eW2, eb2, out, fptr);
}